// Round 1
// baseline (61.958 us; speedup 1.0000x reference)
//
#include <hip/hip_runtime.h>
#include <math.h>

// HSTU positional encoder:
//   out[t, :] = emb[t, :] * sqrt(D) + pos_weight[pos(t), :]
//   pos(t) = clip( min(seq_lengths[seg], P-1) - (t - seq_offsets[seg]), 0, P-1 )
// D = 512 (128 float4 per row). Memory-bound; single fused kernel, float4 I/O.

constexpr int D_DIM = 512;
constexpr int D4 = D_DIM / 4;   // 128 float4 per row

__global__ void hstu_pos_enc_kernel(const int* __restrict__ seq_lengths,
                                    const int* __restrict__ seq_offsets,
                                    const float* __restrict__ emb,
                                    const float* __restrict__ wt,
                                    float* __restrict__ out,
                                    int nelem4,      // total * D4
                                    int nseq,        // B
                                    int maxpos,      // P
                                    float alpha)
{
    const float4* __restrict__ emb4 = reinterpret_cast<const float4*>(emb);
    const float4* __restrict__ wt4  = reinterpret_cast<const float4*>(wt);
    float4* __restrict__ out4       = reinterpret_cast<float4*>(out);

    int stride = gridDim.x * blockDim.x;
    for (int idx = blockIdx.x * blockDim.x + threadIdx.x;
         idx < nelem4; idx += stride) {
        int tok = idx >> 7;        // idx / D4   (D4 == 128)
        int c4  = idx & (D4 - 1);  // idx % D4

        // Segment of this token: largest b with seq_offsets[b] <= tok.
        // seq_offsets addresses are wave-uniform -> scalar loads; B is tiny.
        int seg = 0;
        for (int b = 1; b < nseq; ++b) {
            if (seq_offsets[b] <= tok) seg = b;
        }
        int start = seq_offsets[seg];
        int high  = min(seq_lengths[seg], maxpos - 1);
        int pos   = high - (tok - start);
        pos = min(max(pos, 0), maxpos - 1);

        float4 e = emb4[idx];
        float4 w = wt4[pos * D4 + c4];
        float4 o;
        o.x = fmaf(e.x, alpha, w.x);
        o.y = fmaf(e.y, alpha, w.y);
        o.z = fmaf(e.z, alpha, w.z);
        o.w = fmaf(e.w, alpha, w.w);
        out4[idx] = o;
    }
}

extern "C" void kernel_launch(void* const* d_in, const int* in_sizes, int n_in,
                              void* d_out, int out_size, void* d_ws, size_t ws_size,
                              hipStream_t stream)
{
    // Inputs per setup_inputs() order:
    // 0: max_seq_len (scalar, unused by the math)
    // 1: seq_lengths (int32[B])
    // 2: seq_offsets (int32[B+1])
    // 3: seq_embeddings (f32[TOTAL, D])
    // 4: pos_weight (f32[P, D])
    const int*   seq_lengths = (const int*)d_in[1];
    const int*   seq_offsets = (const int*)d_in[2];
    const float* emb         = (const float*)d_in[3];
    const float* wt          = (const float*)d_in[4];
    float*       out         = (float*)d_out;

    int B     = in_sizes[1];
    int total = in_sizes[3] / D_DIM;
    int P     = in_sizes[4] / D_DIM;
    float alpha = sqrtf((float)D_DIM);

    int nelem4 = total * D4;
    const int block = 256;
    int grid = (nelem4 + block - 1) / block;
    if (grid > 8192) grid = 8192;   // grid-stride the rest

    hstu_pos_enc_kernel<<<dim3(grid), dim3(block), 0, stream>>>(
        seq_lengths, seq_offsets, emb, wt, out, nelem4, B, P, alpha);
}

// Round 3
// 60.291 us; speedup vs baseline: 1.0277x; 1.0277x over previous
//
#include <hip/hip_runtime.h>
#include <math.h>

// HSTU positional encoder:
//   out[t, :] = emb[t, :] * sqrt(D) + pos_weight[pos(t), :]
//   pos(t) = clip( min(seq_lengths[seg], P-1) - (t - seq_offsets[seg]), 0, P-1 )
// D = 512 (128 float4 per row). Memory-bound.
//
// R3: same plan as R2 but with a clang ext_vector float4 so the
// nontemporal builtins compile (HIP_vector_type float4 is a struct and
// is rejected by __builtin_nontemporal_*).

constexpr int D_DIM = 512;
constexpr int D4 = D_DIM / 4;   // 128 f32x4 per row
constexpr int MAXB = 16;        // B in the reference; generic fallback below

typedef float f32x4 __attribute__((ext_vector_type(4)));

__global__ void hstu_pos_enc_kernel(const int* __restrict__ seq_lengths,
                                    const int* __restrict__ seq_offsets,
                                    const float* __restrict__ emb,
                                    const float* __restrict__ wt,
                                    float* __restrict__ out,
                                    int nelem4, int nseq, int maxpos,
                                    float alpha)
{
    const f32x4* __restrict__ emb4 = reinterpret_cast<const f32x4*>(emb);
    const f32x4* __restrict__ wt4  = reinterpret_cast<const f32x4*>(wt);
    f32x4* __restrict__ out4       = reinterpret_cast<f32x4*>(out);

    // Hoist the tiny tables into registers once. Compile-time indices only
    // -> stays in registers; uniform addresses -> s_load.
    int offs[MAXB], highs[MAXB];
#pragma unroll
    for (int b = 0; b < MAXB; ++b) {
        offs[b]  = (b < nseq) ? seq_offsets[b] : 0x7fffffff;
        highs[b] = (b < nseq) ? min(seq_lengths[b], maxpos - 1) : 0;
    }

    int stride = gridDim.x * blockDim.x;
    for (int idx = blockIdx.x * blockDim.x + threadIdx.x;
         idx < nelem4; idx += stride) {
        // tok is wave-uniform: a 64-lane wave covers 64 consecutive f32x4,
        // i.e. half of one 128-f32x4 row -> idx>>7 identical across lanes.
        int tok = __builtin_amdgcn_readfirstlane(idx >> 7);
        int c4  = idx & (D4 - 1);

        // Scalar select chain: largest b with offs[b] <= tok.
        int start = offs[0];
        int high  = highs[0];
#pragma unroll
        for (int b = 1; b < MAXB; ++b) {
            bool c = (offs[b] <= tok);
            start = c ? offs[b]  : start;
            high  = c ? highs[b] : high;
        }
        int pos = high - (tok - start);
        pos = min(max(pos, 0), maxpos - 1);

        f32x4 e = __builtin_nontemporal_load(&emb4[idx]);
        f32x4 w = wt4[pos * D4 + c4];   // cached: table is LLC-resident
        f32x4 o;
        o.x = fmaf(e.x, alpha, w.x);
        o.y = fmaf(e.y, alpha, w.y);
        o.z = fmaf(e.z, alpha, w.z);
        o.w = fmaf(e.w, alpha, w.w);
        __builtin_nontemporal_store(o, &out4[idx]);
    }
}

// Generic fallback for nseq > MAXB (not hit in this bench, kept for safety).
__global__ void hstu_pos_enc_generic(const int* __restrict__ seq_lengths,
                                     const int* __restrict__ seq_offsets,
                                     const float* __restrict__ emb,
                                     const float* __restrict__ wt,
                                     float* __restrict__ out,
                                     int nelem4, int nseq, int maxpos,
                                     float alpha)
{
    const f32x4* __restrict__ emb4 = reinterpret_cast<const f32x4*>(emb);
    const f32x4* __restrict__ wt4  = reinterpret_cast<const f32x4*>(wt);
    f32x4* __restrict__ out4       = reinterpret_cast<f32x4*>(out);

    int stride = gridDim.x * blockDim.x;
    for (int idx = blockIdx.x * blockDim.x + threadIdx.x;
         idx < nelem4; idx += stride) {
        int tok = idx >> 7;
        int c4  = idx & (D4 - 1);
        int seg = 0;
        for (int b = 1; b < nseq; ++b)
            if (seq_offsets[b] <= tok) seg = b;
        int start = seq_offsets[seg];
        int high  = min(seq_lengths[seg], maxpos - 1);
        int pos   = min(max(high - (tok - start), 0), maxpos - 1);
        f32x4 e = emb4[idx];
        f32x4 w = wt4[pos * D4 + c4];
        f32x4 o;
        o.x = fmaf(e.x, alpha, w.x);
        o.y = fmaf(e.y, alpha, w.y);
        o.z = fmaf(e.z, alpha, w.z);
        o.w = fmaf(e.w, alpha, w.w);
        out4[idx] = o;
    }
}

extern "C" void kernel_launch(void* const* d_in, const int* in_sizes, int n_in,
                              void* d_out, int out_size, void* d_ws, size_t ws_size,
                              hipStream_t stream)
{
    // Inputs (setup_inputs order):
    // 0: max_seq_len scalar, 1: seq_lengths[B], 2: seq_offsets[B+1],
    // 3: seq_embeddings[TOTAL,D] f32, 4: pos_weight[P,D] f32
    const int*   seq_lengths = (const int*)d_in[1];
    const int*   seq_offsets = (const int*)d_in[2];
    const float* emb         = (const float*)d_in[3];
    const float* wt          = (const float*)d_in[4];
    float*       out         = (float*)d_out;

    int B     = in_sizes[1];
    int P     = in_sizes[4] / D_DIM;
    int total = in_sizes[3] / D_DIM;
    float alpha = sqrtf((float)D_DIM);

    int nelem4 = total * D4;
    const int block = 256;
    int grid = (nelem4 + block - 1) / block;
    if (grid > 2048) grid = 2048;   // 8 blocks/CU, grid-stride the rest

    if (B <= MAXB) {
        hstu_pos_enc_kernel<<<dim3(grid), dim3(block), 0, stream>>>(
            seq_lengths, seq_offsets, emb, wt, out, nelem4, B, P, alpha);
    } else {
        hstu_pos_enc_generic<<<dim3(grid), dim3(block), 0, stream>>>(
            seq_lengths, seq_offsets, emb, wt, out, nelem4, B, P, alpha);
    }
}